// Round 1
// baseline (89.895 us; speedup 1.0000x reference)
//
#include <hip/hip_runtime.h>
#include <math.h>

#define B_TOTAL 16384
#define RR 64
#define KK_TOT 256      // 4*R
#define MM 512
#define ROWS 32         // batch rows per block
#define KC 8            // K chunk staged in LDS
#define ESP 257         // emb LDS row stride (pad)
#define SSP 516         // S LDS row stride (pad, multiple of 4 for float4)

__global__ __launch_bounds__(256, 2)
void nest2_fused(const int* __restrict__ indices,
                 const float* __restrict__ v0, const float* __restrict__ v1,
                 const float* __restrict__ v2, const float* __restrict__ v3,
                 const float* __restrict__ S, const float* __restrict__ bvec,
                 const float* __restrict__ w_mu, float* __restrict__ out)
{
    __shared__ int ind_lds[ROWS * 4];
    __shared__ float emb_lds[ROWS * ESP];
    __shared__ alignas(16) float s_lds[KC * SSP];

    const int tid = threadIdx.x;
    const int rowBase = blockIdx.x * ROWS;

    if (tid < ROWS * 4) ind_lds[tid] = indices[rowBase * 4 + tid];
    __syncthreads();

    // ---- stick-breaking: emb_lds[row][mod*64 + r] ----
    const int wid  = tid >> 6;
    const int lane = tid & 63;
    #pragma unroll
    for (int it = 0; it < 32; ++it) {
        const int p   = wid * 32 + it;     // (row, mod) pair
        const int row = p >> 2;
        const int mod = p & 3;
        const float* vt = (mod == 0) ? v0 : (mod == 1) ? v1 : (mod == 2) ? v2 : v3;
        const int idx = ind_lds[p];
        const float vh = vt[idx * RR + lane];

        // log_sigmoid(x) = min(x,0) - log1p(exp(-|x|))
        const float l1p = log1pf(expf(-fabsf(vh)));
        const float lv  = fminf(vh, 0.f) - l1p;   // log sigmoid(vh)
        const float lvm = fminf(-vh, 0.f) - l1p;  // log sigmoid(-vh)

        // inclusive scan of lvm across 64 lanes
        float csum = lvm;
        #pragma unroll
        for (int off = 1; off < 64; off <<= 1) {
            const float t = __shfl_up(csum, off, 64);
            if (lane >= off) csum += t;
        }
        // exclusive = inclusive - self
        emb_lds[row * ESP + mod * RR + lane] = expf(lv + csum - lvm);
    }

    // ---- GEMM: phi_lin[r][c] = sum_k emb[r][k] * S[c][k] ----
    const int cg = tid & 31;   // 32 column groups; cols = cg*4 + q + 128*j
    const int rg = tid >> 5;   // 8 row groups x 4 rows

    float acc[4][16];
    #pragma unroll
    for (int i = 0; i < 4; ++i)
        #pragma unroll
        for (int j = 0; j < 16; ++j) acc[i][j] = 0.f;

    for (int ko = 0; ko < KK_TOT; ko += KC) {
        __syncthreads();
        // stage S[ 0..511 ][ ko..ko+7 ] -> s_lds[kk][c]
        #pragma unroll
        for (int pass = 0; pass < 4; ++pass) {
            const int c   = pass * 128 + (tid >> 1);
            const int kk4 = (tid & 1) * 4;
            const float4 sv = *reinterpret_cast<const float4*>(&S[c * KK_TOT + ko + kk4]);
            s_lds[(kk4 + 0) * SSP + c] = sv.x;
            s_lds[(kk4 + 1) * SSP + c] = sv.y;
            s_lds[(kk4 + 2) * SSP + c] = sv.z;
            s_lds[(kk4 + 3) * SSP + c] = sv.w;
        }
        __syncthreads();

        #pragma unroll
        for (int kk = 0; kk < KC; ++kk) {
            float e[4];
            #pragma unroll
            for (int i = 0; i < 4; ++i)
                e[i] = emb_lds[(rg * 4 + i) * ESP + ko + kk];
            #pragma unroll
            for (int j = 0; j < 4; ++j) {
                const float4 s = *reinterpret_cast<const float4*>(&s_lds[kk * SSP + cg * 4 + j * 128]);
                #pragma unroll
                for (int i = 0; i < 4; ++i) {
                    acc[i][j * 4 + 0] = fmaf(e[i], s.x, acc[i][j * 4 + 0]);
                    acc[i][j * 4 + 1] = fmaf(e[i], s.y, acc[i][j * 4 + 1]);
                    acc[i][j * 4 + 2] = fmaf(e[i], s.z, acc[i][j * 4 + 2]);
                    acc[i][j * 4 + 3] = fmaf(e[i], s.w, acc[i][j * 4 + 3]);
                }
            }
        }
    }

    // ---- epilogue: cos/sin, weighted sum, half-wave reduce, sigmoid ----
    float rowsum[4] = {0.f, 0.f, 0.f, 0.f};
    #pragma unroll
    for (int j = 0; j < 4; ++j) {
        #pragma unroll
        for (int q = 0; q < 4; ++q) {
            const int c = cg * 4 + q + j * 128;
            const float bb = bvec[c];
            const float w1 = w_mu[c];
            const float w2 = w_mu[MM + c];
            #pragma unroll
            for (int i = 0; i < 4; ++i) {
                const float phi = acc[i][j * 4 + q] + bb;
                float sn, cs;
                __sincosf(phi, &sn, &cs);
                rowsum[i] = fmaf(cs, w1, fmaf(sn, w2, rowsum[i]));
            }
        }
    }

    // threads sharing rg are a contiguous 32-lane half-wave: butterfly reduce
    #pragma unroll
    for (int i = 0; i < 4; ++i) {
        float v = rowsum[i];
        #pragma unroll
        for (int m = 16; m >= 1; m >>= 1) v += __shfl_xor(v, m, 64);
        rowsum[i] = v;
    }

    if (cg == 0) {
        #pragma unroll
        for (int i = 0; i < 4; ++i) {
            const float x = rowsum[i];
            out[rowBase + rg * 4 + i] = 1.f / (1.f + expf(-x));
        }
    }
}

extern "C" void kernel_launch(void* const* d_in, const int* in_sizes, int n_in,
                              void* d_out, int out_size, void* d_ws, size_t ws_size,
                              hipStream_t stream) {
    const int*   indices = (const int*)d_in[0];
    const float* v0 = (const float*)d_in[1];
    const float* v1 = (const float*)d_in[2];
    const float* v2 = (const float*)d_in[3];
    const float* v3 = (const float*)d_in[4];
    const float* S  = (const float*)d_in[5];
    const float* bb = (const float*)d_in[6];
    const float* w  = (const float*)d_in[7];
    float* out = (float*)d_out;

    dim3 grid(B_TOTAL / ROWS);
    dim3 block(256);
    hipLaunchKernelGGL(nest2_fused, grid, block, 0, stream,
                       indices, v0, v1, v2, v3, S, bb, w, out);
}

// Round 2
// 43.927 us; speedup vs baseline: 2.0465x; 2.0465x over previous
//
#include <hip/hip_runtime.h>
#include <math.h>

#define B_TOTAL 16384
#define RR 64
#define KK 256          // 4*R
#define MM 512
#define ROWS 64         // batch rows per block
#define NCH 8           // K chunks
#define CHK 32          // K per chunk (= MFMA K)
#define ASTR 264        // A LDS row stride in bf16 elems (64B-pad -> 2-way max)
#define SSTR 40         // S LDS row stride in bf16 elems (16B-aligned, 2-way max)

typedef __attribute__((ext_vector_type(8))) short short8;
typedef __attribute__((ext_vector_type(4))) float floatx4;

static __device__ inline ushort f2bf(float x) {
    union { float f; unsigned u; } v; v.f = x;
    unsigned r = v.u + 0x7FFFu + ((v.u >> 16) & 1u);   // RNE
    return (ushort)(r >> 16);
}
static __device__ inline float bf2f(ushort h) {
    union { float f; unsigned u; } v; v.u = ((unsigned)h) << 16;
    return v.f;
}

__global__ __launch_bounds__(512, 2)
void nest2_mfma(const int* __restrict__ indices,
                const float* __restrict__ v0, const float* __restrict__ v1,
                const float* __restrict__ v2, const float* __restrict__ v3,
                const float* __restrict__ S, const float* __restrict__ bvec,
                const float* __restrict__ w_mu, float* __restrict__ out)
{
    __shared__ int ind_lds[ROWS * 4];
    __shared__ alignas(16) ushort Ahi[ROWS * ASTR];
    __shared__ alignas(16) ushort Alo[ROWS * ASTR];
    __shared__ alignas(16) ushort Shi[MM * SSTR];
    __shared__ alignas(16) ushort Slo[MM * SSTR];
    __shared__ float red[8][ROWS];

    const int tid = threadIdx.x;
    const int rowBase = blockIdx.x * ROWS;
    const int wid  = tid >> 6;
    const int lane = tid & 63;
    const int l15  = lane & 15;
    const int lg   = lane >> 4;

    if (tid < ROWS * 4) ind_lds[tid] = indices[rowBase * 4 + tid];
    __syncthreads();

    // ---- stick-breaking -> Ahi/Alo (bf16 hi/lo split of emb) ----
    #pragma unroll
    for (int it = 0; it < 32; ++it) {
        const int p   = wid * 32 + it;     // (row, mod), 256 pairs
        const int row = p >> 2;
        const int mod = p & 3;
        const float* vt = (mod == 0) ? v0 : (mod == 1) ? v1 : (mod == 2) ? v2 : v3;
        const int idx = ind_lds[p];
        const float vh = vt[idx * RR + lane];

        const float l1p = log1pf(expf(-fabsf(vh)));
        const float lv  = fminf(vh, 0.f) - l1p;    // log sigmoid(vh)
        const float lvm = fminf(-vh, 0.f) - l1p;   // log sigmoid(-vh)

        float csum = lvm;
        #pragma unroll
        for (int off = 1; off < 64; off <<= 1) {
            const float t = __shfl_up(csum, off, 64);
            if (lane >= off) csum += t;
        }
        const float x = expf(lv + csum - lvm);

        const ushort h = f2bf(x);
        const ushort l = f2bf(x - bf2f(h));
        Ahi[row * ASTR + mod * RR + lane] = h;
        Alo[row * ASTR + mod * RR + lane] = l;
    }

    // ---- MFMA GEMM: phi[r][c] = sum_k emb[r][k] * S[c][k], 3-pass hi/lo ----
    floatx4 acc[4][4];
    #pragma unroll
    for (int mi = 0; mi < 4; ++mi)
        #pragma unroll
        for (int ni = 0; ni < 4; ++ni)
            acc[mi][ni] = (floatx4){0.f, 0.f, 0.f, 0.f};

    const int wcol0 = wid * 64;   // this wave's 64-col slice

    for (int ch = 0; ch < NCH; ++ch) {
        if (ch) __syncthreads();   // prev MFMA done before S overwrite
        // stage S[0..511][ch*32 .. +32) -> Shi/Slo, fp32->bf16 split inline
        {
            const int kq    = tid & 7;        // k quad: 4 elems
            const int cbase = tid >> 3;       // 0..63
            #pragma unroll
            for (int pass = 0; pass < 8; ++pass) {
                const int c = pass * 64 + cbase;
                const float4 sv = *reinterpret_cast<const float4*>(
                    &S[c * KK + ch * CHK + kq * 4]);
                ushort4 h, l;
                h.x = f2bf(sv.x); l.x = f2bf(sv.x - bf2f(h.x));
                h.y = f2bf(sv.y); l.y = f2bf(sv.y - bf2f(h.y));
                h.z = f2bf(sv.z); l.z = f2bf(sv.z - bf2f(h.z));
                h.w = f2bf(sv.w); l.w = f2bf(sv.w - bf2f(h.w));
                *reinterpret_cast<ushort4*>(&Shi[c * SSTR + kq * 4]) = h;
                *reinterpret_cast<ushort4*>(&Slo[c * SSTR + kq * 4]) = l;
            }
        }
        __syncthreads();

        // fragments: A[m=l15][k=lg*8+j], B[k=lg*8+j][n=l15]
        short8 ah[4], al[4], bh[4], bl[4];
        const int ka = ch * CHK + lg * 8;
        #pragma unroll
        for (int mi = 0; mi < 4; ++mi) {
            ah[mi] = *reinterpret_cast<const short8*>(&Ahi[(mi * 16 + l15) * ASTR + ka]);
            al[mi] = *reinterpret_cast<const short8*>(&Alo[(mi * 16 + l15) * ASTR + ka]);
        }
        #pragma unroll
        for (int ni = 0; ni < 4; ++ni) {
            const int c = wcol0 + ni * 16 + l15;
            bh[ni] = *reinterpret_cast<const short8*>(&Shi[c * SSTR + lg * 8]);
            bl[ni] = *reinterpret_cast<const short8*>(&Slo[c * SSTR + lg * 8]);
        }
        #pragma unroll
        for (int mi = 0; mi < 4; ++mi)
            #pragma unroll
            for (int ni = 0; ni < 4; ++ni) {
                acc[mi][ni] = __builtin_amdgcn_mfma_f32_16x16x32_bf16(ah[mi], bh[ni], acc[mi][ni], 0, 0, 0);
                acc[mi][ni] = __builtin_amdgcn_mfma_f32_16x16x32_bf16(ah[mi], bl[ni], acc[mi][ni], 0, 0, 0);
                acc[mi][ni] = __builtin_amdgcn_mfma_f32_16x16x32_bf16(al[mi], bh[ni], acc[mi][ni], 0, 0, 0);
            }
    }

    // ---- epilogue: +b, sincos, dot w_mu, reduce ----
    float rp[4][4];   // [mi][r]
    #pragma unroll
    for (int mi = 0; mi < 4; ++mi)
        #pragma unroll
        for (int r = 0; r < 4; ++r) rp[mi][r] = 0.f;

    #pragma unroll
    for (int ni = 0; ni < 4; ++ni) {
        const int c = wcol0 + ni * 16 + l15;
        const float bb = bvec[c];
        const float w1 = w_mu[c];
        const float w2 = w_mu[MM + c];
        #pragma unroll
        for (int mi = 0; mi < 4; ++mi)
            #pragma unroll
            for (int r = 0; r < 4; ++r) {
                const float phi = acc[mi][ni][r] + bb;
                float sn, cs;
                __sincosf(phi, &sn, &cs);
                rp[mi][r] = fmaf(cs, w1, fmaf(sn, w2, rp[mi][r]));
            }
    }

    // reduce across the 16 lanes holding the 16 cols of each row
    #pragma unroll
    for (int mi = 0; mi < 4; ++mi)
        #pragma unroll
        for (int r = 0; r < 4; ++r) {
            float v = rp[mi][r];
            v += __shfl_xor(v, 1, 64);
            v += __shfl_xor(v, 2, 64);
            v += __shfl_xor(v, 4, 64);
            v += __shfl_xor(v, 8, 64);
            if (l15 == 0) red[wid][mi * 16 + lg * 4 + r] = v;
        }
    __syncthreads();

    if (tid < ROWS) {
        float s = 0.f;
        #pragma unroll
        for (int w = 0; w < 8; ++w) s += red[w][tid];
        out[rowBase + tid] = 1.f / (1.f + expf(-s));
    }
}

extern "C" void kernel_launch(void* const* d_in, const int* in_sizes, int n_in,
                              void* d_out, int out_size, void* d_ws, size_t ws_size,
                              hipStream_t stream) {
    const int*   indices = (const int*)d_in[0];
    const float* v0 = (const float*)d_in[1];
    const float* v1 = (const float*)d_in[2];
    const float* v2 = (const float*)d_in[3];
    const float* v3 = (const float*)d_in[4];
    const float* S  = (const float*)d_in[5];
    const float* bb = (const float*)d_in[6];
    const float* w  = (const float*)d_in[7];
    float* out = (float*)d_out;

    dim3 grid(B_TOTAL / ROWS);   // 256 blocks, 1/CU
    dim3 block(512);             // 8 waves
    hipLaunchKernelGGL(nest2_mfma, grid, block, 0, stream,
                       indices, v0, v1, v2, v3, S, bb, w, out);
}

// Round 3
// 40.332 us; speedup vs baseline: 2.2289x; 1.0891x over previous
//
#include <hip/hip_runtime.h>
#include <math.h>

#define B_TOTAL 16384
#define RR 64
#define KK 256          // 4*R
#define MM 512
#define ROWS 64         // batch rows per block
#define NCH 8           // K chunks of 32
#define ASTR 264        // A LDS row stride (bf16 elems); 528B rows, 16B-aligned

typedef __attribute__((ext_vector_type(8))) short short8;
typedef __attribute__((ext_vector_type(4))) float floatx4;

static __device__ inline ushort f2bf(float x) {
    union { float f; unsigned u; } v; v.f = x;
    unsigned r = v.u + 0x7FFFu + ((v.u >> 16) & 1u);   // RNE
    return (ushort)(r >> 16);
}
static __device__ inline float bf2f(ushort h) {
    union { float f; unsigned u; } v; v.u = ((unsigned)h) << 16;
    return v.f;
}

// ---- kernel 1: S[512][256] fp32 -> hi/lo bf16, packed in MFMA B-fragment
// order: Bpk[o][c][j] holds S[c][o*8+j]; fragment (ch,lg,ni,l15) reads 16
// consecutive 16B granules -> fully coalesced.
__global__ __launch_bounds__(256)
void conv_S(const float* __restrict__ S, ushort* __restrict__ Bhi,
            ushort* __restrict__ Blo)
{
    const int F = blockIdx.x * 256 + threadIdx.x;   // F = o*512 + c
    const int o = F >> 9;
    const int c = F & 511;
    const float* src = &S[c * KK + o * 8];
    float v[8];
    *reinterpret_cast<float4*>(&v[0]) = *reinterpret_cast<const float4*>(src);
    *reinterpret_cast<float4*>(&v[4]) = *reinterpret_cast<const float4*>(src + 4);
    short8 hv, lv;
    #pragma unroll
    for (int j = 0; j < 8; ++j) {
        const ushort h = f2bf(v[j]);
        hv[j] = (short)h;
        lv[j] = (short)f2bf(v[j] - bf2f(h));
    }
    *reinterpret_cast<short8*>(&Bhi[F * 8]) = hv;
    *reinterpret_cast<short8*>(&Blo[F * 8]) = lv;
}

// ---- kernel 2: fused gather + stick-break + MFMA GEMM + sincos + reduce ----
__global__ __launch_bounds__(512, 2)
void nest2_mfma(const int* __restrict__ indices,
                const float* __restrict__ v0, const float* __restrict__ v1,
                const float* __restrict__ v2, const float* __restrict__ v3,
                const ushort* __restrict__ Bhi, const ushort* __restrict__ Blo,
                const float* __restrict__ bvec, const float* __restrict__ w_mu,
                float* __restrict__ out)
{
    __shared__ int ind_lds[ROWS * 4];
    __shared__ alignas(16) ushort Ahi[ROWS * ASTR];
    __shared__ alignas(16) ushort Alo[ROWS * ASTR];
    __shared__ float red[8][ROWS];

    const int tid = threadIdx.x;
    const int rowBase = blockIdx.x * ROWS;
    const int wid  = tid >> 6;
    const int lane = tid & 63;
    const int l15  = lane & 15;
    const int lg   = lane >> 4;

    if (tid < ROWS * 4) ind_lds[tid] = indices[rowBase * 4 + tid];
    __syncthreads();

    // ---- stick-breaking (product form) -> Ahi/Alo ----
    #pragma unroll
    for (int it = 0; it < 32; ++it) {
        const int p   = wid * 32 + it;     // (row, mod), 256 pairs
        const int row = p >> 2;
        const int mod = p & 3;
        const float* vt = (mod == 0) ? v0 : (mod == 1) ? v1 : (mod == 2) ? v2 : v3;
        const float vh = vt[ind_lds[p] * RR + lane];

        const float e  = __expf(-vh);
        const float u  = 1.f / (1.f + e);   // sigmoid(vh)
        const float um = e * u;             // sigmoid(-vh)

        // inclusive product-scan of um across 64 lanes, then shift -> exclusive
        float pr = um;
        #pragma unroll
        for (int off = 1; off < 64; off <<= 1) {
            const float t = __shfl_up(pr, off, 64);
            if (lane >= off) pr *= t;
        }
        float ex = __shfl_up(pr, 1, 64);
        if (lane == 0) ex = 1.f;
        const float x = u * ex;

        const ushort h = f2bf(x);
        Ahi[row * ASTR + mod * RR + lane] = h;
        Alo[row * ASTR + mod * RR + lane] = f2bf(x - bf2f(h));
    }
    __syncthreads();

    // ---- barrier-free MFMA K-loop: A from LDS, B from global (L2-hot) ----
    floatx4 acc[4][4];
    #pragma unroll
    for (int mi = 0; mi < 4; ++mi)
        #pragma unroll
        for (int ni = 0; ni < 4; ++ni)
            acc[mi][ni] = (floatx4){0.f, 0.f, 0.f, 0.f};

    const int wcol0 = wid * 64;

    #pragma unroll
    for (int ch = 0; ch < NCH; ++ch) {
        short8 ah[4], al[4];
        const int ka = ch * 32 + lg * 8;
        #pragma unroll
        for (int mi = 0; mi < 4; ++mi) {
            ah[mi] = *reinterpret_cast<const short8*>(&Ahi[(mi * 16 + l15) * ASTR + ka]);
            al[mi] = *reinterpret_cast<const short8*>(&Alo[(mi * 16 + l15) * ASTR + ka]);
        }
        #pragma unroll
        for (int ni = 0; ni < 4; ++ni) {
            const int c   = wcol0 + ni * 16 + l15;
            const int off = ((ch * 4 + lg) * 512 + c) * 8;
            const short8 bh = *reinterpret_cast<const short8*>(&Bhi[off]);
            const short8 bl = *reinterpret_cast<const short8*>(&Blo[off]);
            #pragma unroll
            for (int mi = 0; mi < 4; ++mi) {
                acc[mi][ni] = __builtin_amdgcn_mfma_f32_16x16x32_bf16(ah[mi], bh, acc[mi][ni], 0, 0, 0);
                acc[mi][ni] = __builtin_amdgcn_mfma_f32_16x16x32_bf16(ah[mi], bl, acc[mi][ni], 0, 0, 0);
                acc[mi][ni] = __builtin_amdgcn_mfma_f32_16x16x32_bf16(al[mi], bh, acc[mi][ni], 0, 0, 0);
            }
        }
    }

    // ---- epilogue: +b, sincos, dot w_mu, reduce ----
    float rp[4][4];
    #pragma unroll
    for (int mi = 0; mi < 4; ++mi)
        #pragma unroll
        for (int r = 0; r < 4; ++r) rp[mi][r] = 0.f;

    #pragma unroll
    for (int ni = 0; ni < 4; ++ni) {
        const int c = wcol0 + ni * 16 + l15;
        const float bb = bvec[c];
        const float w1 = w_mu[c];
        const float w2 = w_mu[MM + c];
        #pragma unroll
        for (int mi = 0; mi < 4; ++mi)
            #pragma unroll
            for (int r = 0; r < 4; ++r) {
                const float phi = acc[mi][ni][r] + bb;
                float sn, cs;
                __sincosf(phi, &sn, &cs);
                rp[mi][r] = fmaf(cs, w1, fmaf(sn, w2, rp[mi][r]));
            }
    }

    #pragma unroll
    for (int mi = 0; mi < 4; ++mi)
        #pragma unroll
        for (int r = 0; r < 4; ++r) {
            float v = rp[mi][r];
            v += __shfl_xor(v, 1, 64);
            v += __shfl_xor(v, 2, 64);
            v += __shfl_xor(v, 4, 64);
            v += __shfl_xor(v, 8, 64);
            if (l15 == 0) red[wid][mi * 16 + lg * 4 + r] = v;
        }
    __syncthreads();

    if (tid < ROWS) {
        float s = 0.f;
        #pragma unroll
        for (int w = 0; w < 8; ++w) s += red[w][tid];
        out[rowBase + tid] = 1.f / (1.f + expf(-s));
    }
}

extern "C" void kernel_launch(void* const* d_in, const int* in_sizes, int n_in,
                              void* d_out, int out_size, void* d_ws, size_t ws_size,
                              hipStream_t stream) {
    const int*   indices = (const int*)d_in[0];
    const float* v0 = (const float*)d_in[1];
    const float* v1 = (const float*)d_in[2];
    const float* v2 = (const float*)d_in[3];
    const float* v3 = (const float*)d_in[4];
    const float* S  = (const float*)d_in[5];
    const float* bb = (const float*)d_in[6];
    const float* w  = (const float*)d_in[7];
    float* out = (float*)d_out;

    ushort* Bhi = (ushort*)d_ws;               // 512*256 bf16 = 256 KB
    ushort* Blo = Bhi + MM * KK;               // 256 KB

    hipLaunchKernelGGL(conv_S, dim3(MM * KK / (256 * 8)), dim3(256), 0, stream,
                       S, Bhi, Blo);
    hipLaunchKernelGGL(nest2_mfma, dim3(B_TOTAL / ROWS), dim3(512), 0, stream,
                       indices, v0, v1, v2, v3, Bhi, Blo, bb, w, out);
}

// Round 4
// 29.597 us; speedup vs baseline: 3.0373x; 1.3627x over previous
//
#include <hip/hip_runtime.h>
#include <math.h>

#define B_TOTAL 16384
#define RR 64
#define KK 256          // 4*R
#define MM 512
#define ROWS 32         // batch rows per block (2 blocks/CU)
#define NCH 8           // K chunks of 32
#define MI 2            // 16-row M-tiles per block
#define ASTR 264        // A LDS row stride (bf16 elems); 528B rows, 16B-aligned

typedef __attribute__((ext_vector_type(8))) short short8;
typedef __attribute__((ext_vector_type(4))) float floatx4;

static __device__ inline ushort f2bf(float x) {
    union { float f; unsigned u; } v; v.f = x;
    unsigned r = v.u + 0x7FFFu + ((v.u >> 16) & 1u);   // RNE
    return (ushort)(r >> 16);
}
static __device__ inline float bf2f(ushort h) {
    union { float f; unsigned u; } v; v.u = ((unsigned)h) << 16;
    return v.f;
}

// ---- kernel 1: S[512][256] fp32 -> hi/lo bf16 in MFMA B-fragment order ----
__global__ __launch_bounds__(256)
void conv_S(const float* __restrict__ S, ushort* __restrict__ Bhi,
            ushort* __restrict__ Blo)
{
    const int F = blockIdx.x * 256 + threadIdx.x;   // F = o*512 + c
    const int o = F >> 9;
    const int c = F & 511;
    const float* src = &S[c * KK + o * 8];
    float v[8];
    *reinterpret_cast<float4*>(&v[0]) = *reinterpret_cast<const float4*>(src);
    *reinterpret_cast<float4*>(&v[4]) = *reinterpret_cast<const float4*>(src + 4);
    short8 hv, lv;
    #pragma unroll
    for (int j = 0; j < 8; ++j) {
        const ushort h = f2bf(v[j]);
        hv[j] = (short)h;
        lv[j] = (short)f2bf(v[j] - bf2f(h));
    }
    *reinterpret_cast<short8*>(&Bhi[F * 8]) = hv;
    *reinterpret_cast<short8*>(&Blo[F * 8]) = lv;
}

// ---- kernel 2: fused gather + stick-break + MFMA GEMM + sincos + reduce ----
__global__ __launch_bounds__(512, 4)
void nest2_mfma(const int* __restrict__ indices,
                const float* __restrict__ v0, const float* __restrict__ v1,
                const float* __restrict__ v2, const float* __restrict__ v3,
                const ushort* __restrict__ Bhi, const ushort* __restrict__ Blo,
                const float* __restrict__ bvec, const float* __restrict__ w_mu,
                float* __restrict__ out)
{
    __shared__ int ind_lds[ROWS * 4];
    __shared__ alignas(16) ushort Ahi[ROWS * ASTR];
    __shared__ alignas(16) ushort Alo[ROWS * ASTR];
    __shared__ float red[8][ROWS];

    const int tid = threadIdx.x;
    const int rowBase = blockIdx.x * ROWS;
    const int wid  = tid >> 6;
    const int lane = tid & 63;
    const int l15  = lane & 15;
    const int lg   = lane >> 4;

    if (tid < ROWS * 4) ind_lds[tid] = indices[rowBase * 4 + tid];
    __syncthreads();

    // ---- stick-breaking (product form) -> Ahi/Alo ----
    #pragma unroll
    for (int it = 0; it < ROWS * 4 / 8; ++it) {      // 16 iters
        const int p   = wid * (ROWS * 4 / 8) + it;   // (row, mod) pair
        const int row = p >> 2;
        const int mod = p & 3;
        const float* vt = (mod == 0) ? v0 : (mod == 1) ? v1 : (mod == 2) ? v2 : v3;
        const float vh = vt[ind_lds[p] * RR + lane];

        const float e  = __expf(-vh);
        const float u  = 1.f / (1.f + e);   // sigmoid(vh)
        const float um = e * u;             // sigmoid(-vh)

        // inclusive product-scan of um across 64 lanes, then shift -> exclusive
        float pr = um;
        #pragma unroll
        for (int off = 1; off < 64; off <<= 1) {
            const float t = __shfl_up(pr, off, 64);
            if (lane >= off) pr *= t;
        }
        float ex = __shfl_up(pr, 1, 64);
        if (lane == 0) ex = 1.f;
        const float x = u * ex;

        const ushort h = f2bf(x);
        Ahi[row * ASTR + mod * RR + lane] = h;
        Alo[row * ASTR + mod * RR + lane] = f2bf(x - bf2f(h));
    }
    __syncthreads();

    // ---- barrier-free MFMA K-loop: A from LDS, B from global (L2-hot) ----
    floatx4 acc[MI][4];
    #pragma unroll
    for (int mi = 0; mi < MI; ++mi)
        #pragma unroll
        for (int ni = 0; ni < 4; ++ni)
            acc[mi][ni] = (floatx4){0.f, 0.f, 0.f, 0.f};

    const int wcol0 = wid * 64;

    #pragma unroll
    for (int ch = 0; ch < NCH; ++ch) {
        short8 ah[MI], al[MI];
        const int ka = ch * 32 + lg * 8;
        #pragma unroll
        for (int mi = 0; mi < MI; ++mi) {
            ah[mi] = *reinterpret_cast<const short8*>(&Ahi[(mi * 16 + l15) * ASTR + ka]);
            al[mi] = *reinterpret_cast<const short8*>(&Alo[(mi * 16 + l15) * ASTR + ka]);
        }
        #pragma unroll
        for (int ni = 0; ni < 4; ++ni) {
            const int c   = wcol0 + ni * 16 + l15;
            const int off = ((ch * 4 + lg) * 512 + c) * 8;
            const short8 bh = *reinterpret_cast<const short8*>(&Bhi[off]);
            const short8 bl = *reinterpret_cast<const short8*>(&Blo[off]);
            #pragma unroll
            for (int mi = 0; mi < MI; ++mi) {
                acc[mi][ni] = __builtin_amdgcn_mfma_f32_16x16x32_bf16(ah[mi], bh, acc[mi][ni], 0, 0, 0);
                acc[mi][ni] = __builtin_amdgcn_mfma_f32_16x16x32_bf16(ah[mi], bl, acc[mi][ni], 0, 0, 0);
                acc[mi][ni] = __builtin_amdgcn_mfma_f32_16x16x32_bf16(al[mi], bh, acc[mi][ni], 0, 0, 0);
            }
        }
    }

    // ---- epilogue: +b, sincos, dot w_mu, reduce ----
    float rp[MI][4];
    #pragma unroll
    for (int mi = 0; mi < MI; ++mi)
        #pragma unroll
        for (int r = 0; r < 4; ++r) rp[mi][r] = 0.f;

    #pragma unroll
    for (int ni = 0; ni < 4; ++ni) {
        const int c = wcol0 + ni * 16 + l15;
        const float bb = bvec[c];
        const float w1 = w_mu[c];
        const float w2 = w_mu[MM + c];
        #pragma unroll
        for (int mi = 0; mi < MI; ++mi)
            #pragma unroll
            for (int r = 0; r < 4; ++r) {
                const float phi = acc[mi][ni][r] + bb;
                float sn, cs;
                __sincosf(phi, &sn, &cs);
                rp[mi][r] = fmaf(cs, w1, fmaf(sn, w2, rp[mi][r]));
            }
    }

    #pragma unroll
    for (int mi = 0; mi < MI; ++mi)
        #pragma unroll
        for (int r = 0; r < 4; ++r) {
            float v = rp[mi][r];
            v += __shfl_xor(v, 1, 64);
            v += __shfl_xor(v, 2, 64);
            v += __shfl_xor(v, 4, 64);
            v += __shfl_xor(v, 8, 64);
            if (l15 == 0) red[wid][mi * 16 + lg * 4 + r] = v;
        }
    __syncthreads();

    if (tid < ROWS) {
        float s = 0.f;
        #pragma unroll
        for (int w = 0; w < 8; ++w) s += red[w][tid];
        out[rowBase + tid] = 1.f / (1.f + expf(-s));
    }
}

extern "C" void kernel_launch(void* const* d_in, const int* in_sizes, int n_in,
                              void* d_out, int out_size, void* d_ws, size_t ws_size,
                              hipStream_t stream) {
    const int*   indices = (const int*)d_in[0];
    const float* v0 = (const float*)d_in[1];
    const float* v1 = (const float*)d_in[2];
    const float* v2 = (const float*)d_in[3];
    const float* v3 = (const float*)d_in[4];
    const float* S  = (const float*)d_in[5];
    const float* bb = (const float*)d_in[6];
    const float* w  = (const float*)d_in[7];
    float* out = (float*)d_out;

    ushort* Bhi = (ushort*)d_ws;               // 512*256 bf16 = 256 KB
    ushort* Blo = Bhi + MM * KK;               // 256 KB

    hipLaunchKernelGGL(conv_S, dim3(MM * KK / (256 * 8)), dim3(256), 0, stream,
                       S, Bhi, Blo);
    hipLaunchKernelGGL(nest2_mfma, dim3(B_TOTAL / ROWS), dim3(512), 0, stream,
                       indices, v0, v1, v2, v3, Bhi, Blo, bb, w, out);
}

// Round 5
// 28.535 us; speedup vs baseline: 3.1504x; 1.0372x over previous
//
#include <hip/hip_runtime.h>
#include <math.h>

#define B_TOTAL 16384
#define RR 64
#define KK 256          // 4*R
#define MM 512
#define ROWS 32         // batch rows per block (2 blocks/CU)
#define NCH 8           // K chunks of 32
#define MI 2            // 16-row M-tiles per wave
#define ASTR 264        // A LDS row stride (bf16 elems)
#define INV2PI 0.15915494309189535f

typedef __attribute__((ext_vector_type(8))) short short8;
typedef __attribute__((ext_vector_type(4))) float floatx4;

static __device__ inline ushort f2bf(float x) {
    union { float f; unsigned u; } v; v.f = x;
    unsigned r = v.u + 0x7FFFu + ((v.u >> 16) & 1u);   // RNE
    return (ushort)(r >> 16);
}
static __device__ inline float bf2f(ushort h) {
    union { float f; unsigned u; } v; v.u = ((unsigned)h) << 16;
    return v.f;
}

// DPP mov with multiplicative identity for invalid/unwritten lanes
template<int CTRL, int RMASK>
static __device__ inline float dpp_mov1(float src) {
    int s = __builtin_bit_cast(int, src);
    int o = __builtin_bit_cast(int, 1.0f);
    int r = __builtin_amdgcn_update_dpp(o, s, CTRL, RMASK, 0xF, false);
    return __builtin_bit_cast(float, r);
}
template<int CTRL>
static __device__ inline float dpp_swap(float src) {
    int s = __builtin_bit_cast(int, src);
    int r = __builtin_amdgcn_update_dpp(s, s, CTRL, 0xF, 0xF, false);
    return __builtin_bit_cast(float, r);
}
// sum over each 16-lane group (all 16 lanes end with the sum)
static __device__ inline float red16(float x) {
    x += dpp_swap<0xB1>(x);    // quad_perm [1,0,3,2]  (xor 1)
    x += dpp_swap<0x4E>(x);    // quad_perm [2,3,0,1]  (xor 2)
    x += dpp_swap<0x141>(x);   // row_half_mirror      (xor 4-group)
    x += dpp_swap<0x140>(x);   // row_mirror           (xor 8-group)
    return x;
}

// ---- kernel 1: S -> hi/lo bf16 of S/(2*pi), MFMA B-fragment order ----
__global__ __launch_bounds__(256)
void conv_S(const float* __restrict__ S, ushort* __restrict__ Bhi,
            ushort* __restrict__ Blo)
{
    const int F = blockIdx.x * 256 + threadIdx.x;   // F = o*512 + c
    const int o = F >> 9;
    const int c = F & 511;
    const float* src = &S[c * KK + o * 8];
    float v[8];
    *reinterpret_cast<float4*>(&v[0]) = *reinterpret_cast<const float4*>(src);
    *reinterpret_cast<float4*>(&v[4]) = *reinterpret_cast<const float4*>(src + 4);
    short8 hv, lv;
    #pragma unroll
    for (int j = 0; j < 8; ++j) {
        const float sv = v[j] * INV2PI;   // pre-scale: sincos in revolutions
        const ushort h = f2bf(sv);
        hv[j] = (short)h;
        lv[j] = (short)f2bf(sv - bf2f(h));
    }
    *reinterpret_cast<short8*>(&Bhi[F * 8]) = hv;
    *reinterpret_cast<short8*>(&Blo[F * 8]) = lv;
}

// ---- kernel 2: gather + stick-break + MFMA + sincos + reduce ----
__global__ __launch_bounds__(512, 4)
void nest2_mfma(const int* __restrict__ indices,
                const float* __restrict__ v0, const float* __restrict__ v1,
                const float* __restrict__ v2, const float* __restrict__ v3,
                const ushort* __restrict__ Bhi, const ushort* __restrict__ Blo,
                const float* __restrict__ bvec, const float* __restrict__ w_mu,
                float* __restrict__ out)
{
    __shared__ alignas(16) ushort Ahi[ROWS * ASTR];
    __shared__ alignas(16) ushort Alo[ROWS * ASTR];
    __shared__ float red[8][ROWS];

    const int tid = threadIdx.x;
    const int rowBase = blockIdx.x * ROWS;
    const int wid  = __builtin_amdgcn_readfirstlane(tid >> 6);
    const int lane = tid & 63;
    const int l15  = lane & 15;
    const int lg   = lane >> 4;
    const int wcol0 = wid * 64;

    // ---- gather loads (addresses scalar per wave -> coalesced rows) ----
    const int* ip = indices + rowBase * 4 + wid * 16;
    const float* vts[4] = {v0, v1, v2, v3};
    float vh[16];
    #pragma unroll
    for (int it = 0; it < 16; ++it) {
        const int mod = it & 3;            // wid*16 ≡ 0 (mod 4)
        vh[it] = vts[mod][ip[it] * RR + lane];
    }

    // ---- prefetch B chunk 0 (independent of LDS; hides under scan) ----
    short8 cbh[4], cbl[4];
    #pragma unroll
    for (int ni = 0; ni < 4; ++ni) {
        const int off = ((0 * 4 + lg) * 512 + wcol0 + ni * 16 + l15) * 8;
        cbh[ni] = *reinterpret_cast<const short8*>(&Bhi[off]);
        cbl[ni] = *reinterpret_cast<const short8*>(&Blo[off]);
    }

    // ---- stick-breaking via DPP product-scan ----
    #pragma unroll
    for (int it = 0; it < 16; ++it) {
        const int p   = wid * 16 + it;
        const int row = p >> 2;
        const int mod = p & 3;
        const float t  = __expf(vh[it]);                    // e^{vh}
        const float um = __builtin_amdgcn_rcpf(1.f + t);    // sigmoid(-vh)
        float pr = um;                                      // inclusive scan
        pr *= dpp_mov1<0x111, 0xF>(pr);   // row_shr:1
        pr *= dpp_mov1<0x112, 0xF>(pr);   // row_shr:2
        pr *= dpp_mov1<0x114, 0xF>(pr);   // row_shr:4
        pr *= dpp_mov1<0x118, 0xF>(pr);   // row_shr:8
        pr *= dpp_mov1<0x142, 0xA>(pr);   // row_bcast:15 -> rows 1,3
        pr *= dpp_mov1<0x143, 0xC>(pr);   // row_bcast:31 -> rows 2,3
        const float x = t * pr;           // sigmoid(vh) * exclusive-prod
        const ushort h = f2bf(x);
        Ahi[row * ASTR + mod * RR + lane] = h;
        Alo[row * ASTR + mod * RR + lane] = f2bf(x - bf2f(h));
    }
    __syncthreads();

    // ---- MFMA K-loop: A from LDS, B from global (L2-hot) ----
    floatx4 acc[MI][4];
    #pragma unroll
    for (int mi = 0; mi < MI; ++mi)
        #pragma unroll
        for (int ni = 0; ni < 4; ++ni)
            acc[mi][ni] = (floatx4){0.f, 0.f, 0.f, 0.f};

    #pragma unroll
    for (int ch = 0; ch < NCH; ++ch) {
        short8 ah[MI], al[MI];
        const int ka = ch * 32 + lg * 8;
        #pragma unroll
        for (int mi = 0; mi < MI; ++mi) {
            ah[mi] = *reinterpret_cast<const short8*>(&Ahi[(mi * 16 + l15) * ASTR + ka]);
            al[mi] = *reinterpret_cast<const short8*>(&Alo[(mi * 16 + l15) * ASTR + ka]);
        }
        #pragma unroll
        for (int ni = 0; ni < 4; ++ni) {
            short8 bh, bl;
            if (ch == 0) { bh = cbh[ni]; bl = cbl[ni]; }
            else {
                const int off = ((ch * 4 + lg) * 512 + wcol0 + ni * 16 + l15) * 8;
                bh = *reinterpret_cast<const short8*>(&Bhi[off]);
                bl = *reinterpret_cast<const short8*>(&Blo[off]);
            }
            #pragma unroll
            for (int mi = 0; mi < MI; ++mi) {
                acc[mi][ni] = __builtin_amdgcn_mfma_f32_16x16x32_bf16(ah[mi], bh, acc[mi][ni], 0, 0, 0);
                acc[mi][ni] = __builtin_amdgcn_mfma_f32_16x16x32_bf16(ah[mi], bl, acc[mi][ni], 0, 0, 0);
                acc[mi][ni] = __builtin_amdgcn_mfma_f32_16x16x32_bf16(al[mi], bh, acc[mi][ni], 0, 0, 0);
            }
        }
    }

    // ---- epilogue: +b', hw sincos (revolutions), dot w_mu, reduce ----
    float rp[MI][4];
    #pragma unroll
    for (int mi = 0; mi < MI; ++mi)
        #pragma unroll
        for (int r = 0; r < 4; ++r) rp[mi][r] = 0.f;

    #pragma unroll
    for (int ni = 0; ni < 4; ++ni) {
        const int c = wcol0 + ni * 16 + l15;
        const float bb = bvec[c] * INV2PI;
        const float w1 = w_mu[c];
        const float w2 = w_mu[MM + c];
        #pragma unroll
        for (int mi = 0; mi < MI; ++mi)
            #pragma unroll
            for (int r = 0; r < 4; ++r) {
                const float psi = acc[mi][ni][r] + bb;      // revolutions
                const float sn = __builtin_amdgcn_sinf(psi);
                const float cs = __builtin_amdgcn_cosf(psi);
                rp[mi][r] = fmaf(cs, w1, fmaf(sn, w2, rp[mi][r]));
            }
    }

    #pragma unroll
    for (int mi = 0; mi < MI; ++mi)
        #pragma unroll
        for (int r = 0; r < 4; ++r) {
            const float v = red16(rp[mi][r]);
            if (l15 == 0) red[wid][mi * 16 + lg * 4 + r] = v;
        }
    __syncthreads();

    if (tid < ROWS) {
        float s = 0.f;
        #pragma unroll
        for (int w = 0; w < 8; ++w) s += red[w][tid];
        out[rowBase + tid] = 1.f / (1.f + expf(-s));
    }
}

extern "C" void kernel_launch(void* const* d_in, const int* in_sizes, int n_in,
                              void* d_out, int out_size, void* d_ws, size_t ws_size,
                              hipStream_t stream) {
    const int*   indices = (const int*)d_in[0];
    const float* v0 = (const float*)d_in[1];
    const float* v1 = (const float*)d_in[2];
    const float* v2 = (const float*)d_in[3];
    const float* v3 = (const float*)d_in[4];
    const float* S  = (const float*)d_in[5];
    const float* bb = (const float*)d_in[6];
    const float* w  = (const float*)d_in[7];
    float* out = (float*)d_out;

    ushort* Bhi = (ushort*)d_ws;               // 512*256 bf16 = 256 KB
    ushort* Blo = Bhi + MM * KK;               // 256 KB

    hipLaunchKernelGGL(conv_S, dim3(MM * KK / (256 * 8)), dim3(256), 0, stream,
                       S, Bhi, Blo);
    hipLaunchKernelGGL(nest2_mfma, dim3(B_TOTAL / ROWS), dim3(512), 0, stream,
                       indices, v0, v1, v2, v3, Bhi, Blo, bb, w, out);
}